// Round 4
// baseline (2366.951 us; speedup 1.0000x reference)
//
#include <hip/hip_runtime.h>
#include <hip/hip_fp16.h>
#include <math.h>

#define NN 50000
#define EE 800000
#define BB 250
#define TT 8
#define CIN 32
#define COUT 64
#define NPG 200          // nodes per graph (N/B)
#define SCAN_B 256
#define NBLK 196         // ceil(50000/256)
#define GC (BB * COUT)   // 16000 floats per pool slab

#define DPB 64           // dests per block in tiled aggregation
#define NDB 782          // ceil(NN/DPB)
#define SLICE_SH 13      // source-slice = 8192 nodes = 2MB of 256B rows (<= half XCD L2)
#define NPASS 7          // ceil(50000/8192)

// pack/unpack CSR entry: low 16 = src node (NN<65536), high 16 = fp16 weight
__device__ __forceinline__ float unpack_w(unsigned int v) {
    union { unsigned short u; __half h; } cv;
    cv.u = (unsigned short)(v >> 16);
    return __half2float(cv.h);
}

// ---------------- setup kernels (graph structure, once per call) ----------------

__global__ void init_deg(int* deg, int* cursor) {
    int n = blockIdx.x * 256 + threadIdx.x;
    if (n < NN) { deg[n] = 1; cursor[n] = 0; }
}

__global__ void count_deg(const int* dst, int* deg) {
    int e = blockIdx.x * 256 + threadIdx.x;
    if (e < EE) atomicAdd(&deg[dst[e]], 1);
}

__global__ void compute_dinv(const int* deg, float* dinv) {
    int n = blockIdx.x * 256 + threadIdx.x;
    if (n < NN) dinv[n] = rsqrtf((float)deg[n]);
}

__global__ void scan_blocks(const int* deg, int* off, int* bsum) {
    __shared__ int sh[SCAN_B];
    int gid = blockIdx.x * SCAN_B + threadIdx.x;
    int v = (gid < NN) ? (deg[gid] - 1) : 0;
    sh[threadIdx.x] = v;
    __syncthreads();
    for (int s = 1; s < SCAN_B; s <<= 1) {
        int add = (threadIdx.x >= s) ? sh[threadIdx.x - s] : 0;
        __syncthreads();
        sh[threadIdx.x] += add;
        __syncthreads();
    }
    if (gid < NN) off[gid] = sh[threadIdx.x] - v;
    if (threadIdx.x == SCAN_B - 1) bsum[blockIdx.x] = sh[threadIdx.x];
}

__global__ void scan_sums(int* bsum, int* off) {
    __shared__ int sh[SCAN_B];
    int v = (threadIdx.x < NBLK) ? bsum[threadIdx.x] : 0;
    sh[threadIdx.x] = v;
    __syncthreads();
    for (int s = 1; s < SCAN_B; s <<= 1) {
        int add = (threadIdx.x >= s) ? sh[threadIdx.x - s] : 0;
        __syncthreads();
        sh[threadIdx.x] += add;
        __syncthreads();
    }
    if (threadIdx.x < NBLK) bsum[threadIdx.x] = sh[threadIdx.x] - v;
    if (threadIdx.x == 0) off[NN] = EE;
}

__global__ void scan_add(int* off, const int* bsum) {
    int gid = blockIdx.x * SCAN_B + threadIdx.x;
    if (gid < NN) off[gid] += bsum[blockIdx.x];
}

__global__ void fill_csr(const int* src, const int* dst, const int* off,
                         int* cursor, const float* dinv, unsigned int* csrp) {
    int e = blockIdx.x * 256 + threadIdx.x;
    if (e >= EE) return;
    int s = src[e], d = dst[e];
    int p = atomicAdd(&cursor[d], 1);
    union { __half h; unsigned short u; } cv;
    cv.h = __float2half(dinv[s] * dinv[d]);
    csrp[off[d] + p] = (unsigned int)s | ((unsigned int)cv.u << 16);
}

__global__ void scratch_init(float* scr, int ntot) {
    int i = blockIdx.x * 256 + threadIdx.x;
    if (i < ntot) scr[i] = 0.f;
}

// ---------------- compute kernels ----------------

// ONE pass over edges: xa2 chunk-interleaved fp16. Broadcast walk (16B/lane).
__global__ void agg_x_allT16(const float* __restrict__ x, const int* __restrict__ off,
                             const unsigned int* __restrict__ csrp,
                             const float* __restrict__ dinv, __half2* __restrict__ xa2) {
    int lane = threadIdx.x & 63;
    int w = threadIdx.x >> 6;
    int n = blockIdx.x * 4 + w;
    float dn = dinv[n];
    float sw = dn * dn;
    float4 v = ((const float4*)(x + (size_t)n * 256))[lane];
    float4 acc = make_float4(sw * v.x, sw * v.y, sw * v.z, sw * v.w);
    int e0 = off[n], e1 = off[n + 1];
    for (int base = e0; base < e1; base += 64) {
        int idx = base + lane;
        unsigned int cme = (idx < e1) ? csrp[idx] : 0u;
        int cnt = min(64, e1 - base);
        int k = 0;
        for (; k + 3 < cnt; k += 4) {
            unsigned int p0 = __shfl(cme, k, 64),     p1 = __shfl(cme, k + 1, 64);
            unsigned int p2 = __shfl(cme, k + 2, 64), p3 = __shfl(cme, k + 3, 64);
            float4 u0 = ((const float4*)(x + (size_t)(p0 & 0xffff) * 256))[lane];
            float4 u1 = ((const float4*)(x + (size_t)(p1 & 0xffff) * 256))[lane];
            float4 u2 = ((const float4*)(x + (size_t)(p2 & 0xffff) * 256))[lane];
            float4 u3 = ((const float4*)(x + (size_t)(p3 & 0xffff) * 256))[lane];
            float w0 = unpack_w(p0), w1 = unpack_w(p1);
            float w2 = unpack_w(p2), w3 = unpack_w(p3);
            acc.x = fmaf(w0, u0.x, acc.x); acc.y = fmaf(w0, u0.y, acc.y);
            acc.z = fmaf(w0, u0.z, acc.z); acc.w = fmaf(w0, u0.w, acc.w);
            acc.x = fmaf(w1, u1.x, acc.x); acc.y = fmaf(w1, u1.y, acc.y);
            acc.z = fmaf(w1, u1.z, acc.z); acc.w = fmaf(w1, u1.w, acc.w);
            acc.x = fmaf(w2, u2.x, acc.x); acc.y = fmaf(w2, u2.y, acc.y);
            acc.z = fmaf(w2, u2.z, acc.z); acc.w = fmaf(w2, u2.w, acc.w);
            acc.x = fmaf(w3, u3.x, acc.x); acc.y = fmaf(w3, u3.y, acc.y);
            acc.z = fmaf(w3, u3.z, acc.z); acc.w = fmaf(w3, u3.w, acc.w);
        }
        for (; k < cnt; ++k) {
            unsigned int p = __shfl(cme, k, 64);
            float wj = unpack_w(p);
            float4 u = ((const float4*)(x + (size_t)(p & 0xffff) * 256))[lane];
            acc.x = fmaf(wj, u.x, acc.x); acc.y = fmaf(wj, u.y, acc.y);
            acc.z = fmaf(wj, u.z, acc.z); acc.w = fmaf(wj, u.w, acc.w);
        }
    }
    // element flat idx f = 4*lane+k -> (c = f>>3, t = f&7)
    __shared__ float sh[4][TT][33];
    float av[4] = {acc.x, acc.y, acc.z, acc.w};
    #pragma unroll
    for (int k = 0; k < 4; ++k) {
        int f = 4 * lane + k;
        sh[w][f & 7][f >> 3] = av[k];
    }
    __syncthreads();
    // chunk-interleaved write: addr = (chunk*NN + n)*32 + tc*16 + pp
    for (int i = threadIdx.x; i < 512; i += 256) {
        int t = i >> 6;
        int r = i & 63;
        int nl = r >> 4;
        int pp = r & 15;
        xa2[((size_t)(t >> 1) * NN + blockIdx.x * 4 + nl) * 32 + (t & 1) * 16 + pp] =
            __floats2half2_rn(sh[nl][t][2 * pp], sh[nl][t][2 * pp + 1]);
    }
}

// h1 = relu(xa[chunk] W1 + b1), pool, H1[n][tc][pr] = h1 W2 (interleaved out)
__global__ void l1mat2i(const __half2* __restrict__ xa, const float* __restrict__ W1,
                        const float* __restrict__ b1, const float* __restrict__ W2,
                        __half2* __restrict__ H1,
                        float* __restrict__ pmax, float* __restrict__ psum) {
    __shared__ float W1s[CIN * COUT];      // 8 KB
    __shared__ __half2 W2s[COUT * 32];     // 8 KB
    __shared__ float Xs[4][2][CIN];
    __shared__ float tile[4][2][COUT];
    for (int i = threadIdx.x; i < CIN * COUT; i += 256) W1s[i] = W1[i];
    for (int i = threadIdx.x; i < COUT * 32; i += 256) {
        int k = i >> 5, pr = i & 31;
        W2s[i] = __floats2half2_rn(W2[k * COUT + 2 * pr], W2[k * COUT + 2 * pr + 1]);
    }
    if (threadIdx.x < 128) {
        int nl = threadIdx.x >> 5, idx = threadIdx.x & 31;
        int tc = idx >> 4, pp = idx & 15;
        float2 v = __half22float2(xa[((size_t)blockIdx.x * 4 + nl) * 32 + idx]);
        Xs[nl][tc][2 * pp] = v.x;
        Xs[nl][tc][2 * pp + 1] = v.y;
    }
    __syncthreads();
    int co = threadIdx.x & 63;
    int nl = threadIdx.x >> 6;
    float a0 = b1[co], a1 = b1[co];
    #pragma unroll
    for (int k = 0; k < CIN; ++k) {
        float wv = W1s[k * COUT + co];
        a0 = fmaf(Xs[nl][0][k], wv, a0);
        a1 = fmaf(Xs[nl][1][k], wv, a1);
    }
    tile[nl][0][co] = fmaxf(a0, 0.f);
    tile[nl][1][co] = fmaxf(a1, 0.f);
    __syncthreads();
    if (threadIdx.x < 128) {
        int c = threadIdx.x & 63, tc = threadIdx.x >> 6;
        float m = fmaxf(fmaxf(tile[0][tc][c], tile[1][tc][c]),
                        fmaxf(tile[2][tc][c], tile[3][tc][c]));
        float s = tile[0][tc][c] + tile[1][tc][c] + tile[2][tc][c] + tile[3][tc][c];
        int g = blockIdx.x / 50;
        atomicMax((int*)&pmax[tc * GC + g * COUT + c], __float_as_int(m));
        atomicAdd(&psum[tc * GC + g * COUT + c], s);
    }
    {   // W2 matmul: 256 thr = 8 rows (4 nodes x 2 tc) x 32 pairs
        int row = threadIdx.x >> 5;
        int pr = threadIdx.x & 31;
        int nl2 = row >> 1, tc2 = row & 1;
        float b0 = 0.f, bb1 = 0.f;
        #pragma unroll
        for (int k = 0; k < COUT; ++k) {
            float xv = tile[nl2][tc2][k];
            float2 wv = __half22float2(W2s[k * 32 + pr]);
            b0 = fmaf(xv, wv.x, b0);
            bb1 = fmaf(xv, wv.y, bb1);
        }
        H1[((size_t)blockIdx.x * 4 + nl2) * 64 + tc2 * 32 + pr] =
            __floats2half2_rn(b0, bb1);
    }
}

// Source-slice-tiled 2-t aggregation. Block owns DPB=64 dests, LDS fp32
// accumulators [64][128] persist across NPASS source-slice passes. Per pass,
// only edges whose source lies in slice p (8192 nodes = 2MB of rows) are
// gathered; all ~3 resident blocks/CU sweep slices in the same order, so the
// ~16x re-read traffic of each row is served from the XCD L2 instead of the
// L3/fabric (measured ceiling ~2.8 TB/s for random 256B granules).
// Ballot-compacted walk: total gathered edges unchanged; tail lanes carry
// cme=0 (slice 0, weight +0.0, row 0) -> self-masking.
template <int FUSE>
__global__ void agg2t(const __half2* __restrict__ Hin, const int* __restrict__ off,
                      const unsigned int* __restrict__ csrp,
                      const float* __restrict__ dinv, const float* __restrict__ b,
                      const float* __restrict__ W, __half2* __restrict__ Hout,
                      float* __restrict__ pmax, float* __restrict__ psum) {
    __shared__ float accf[DPB][128];           // 32 KB
    __shared__ __half2 Ws[FUSE ? COUT * 32 : 1];
    if (FUSE)
        for (int i = threadIdx.x; i < COUT * 32; i += 256) {
            int k = i >> 5, pr = i & 31;
            Ws[i] = __floats2half2_rn(W[k * COUT + 2 * pr], W[k * COUT + 2 * pr + 1]);
        }
    int lane = threadIdx.x & 63;
    int w = threadIdx.x >> 6;
    int n0 = blockIdx.x * DPB;

    // init accumulators with the self-loop term (wave owns dests 16w..16w+15)
    for (int i = 0; i < 16; ++i) {
        int dl = 16 * w + i;
        int n = n0 + dl;
        float2 sv = make_float2(0.f, 0.f);
        float sw = 0.f;
        if (n < NN) {
            float dn = dinv[n];
            sw = dn * dn;
            sv = __half22float2(Hin[(size_t)n * 64 + lane]);
        }
        accf[dl][2 * lane]     = sw * sv.x;
        accf[dl][2 * lane + 1] = sw * sv.y;
    }

    for (int pass = 0; pass < NPASS; ++pass) {
        for (int i = 0; i < 16; ++i) {
            int dl = 16 * w + i;
            int n = n0 + dl;
            if (n >= NN) break;                 // wave-uniform
            float ax = 0.f, ay = 0.f;
            int e0 = off[n], e1 = off[n + 1];
            for (int base = e0; base < e1; base += 64) {
                int idx = base + lane;
                unsigned int cme = (idx < e1) ? csrp[idx] : 0u;
                bool inpass = (((cme & 0xffffu) >> SLICE_SH) == (unsigned)pass);
                unsigned long long m = __ballot(inpass);
                while (m) {
                    unsigned int c0, c1 = 0, c2 = 0, c3 = 0;
                    { int k = __builtin_ctzll(m); m &= m - 1;
                      c0 = __builtin_amdgcn_readlane(cme, k); }
                    if (m) { int k = __builtin_ctzll(m); m &= m - 1;
                             c1 = __builtin_amdgcn_readlane(cme, k); }
                    if (m) { int k = __builtin_ctzll(m); m &= m - 1;
                             c2 = __builtin_amdgcn_readlane(cme, k); }
                    if (m) { int k = __builtin_ctzll(m); m &= m - 1;
                             c3 = __builtin_amdgcn_readlane(cme, k); }
                    __half2 u0 = Hin[(size_t)(c0 & 0xffff) * 64 + lane];
                    __half2 u1 = Hin[(size_t)(c1 & 0xffff) * 64 + lane];
                    __half2 u2 = Hin[(size_t)(c2 & 0xffff) * 64 + lane];
                    __half2 u3 = Hin[(size_t)(c3 & 0xffff) * 64 + lane];
                    float w0 = unpack_w(c0), w1 = unpack_w(c1);
                    float w2 = unpack_w(c2), w3 = unpack_w(c3);
                    float2 f0 = __half22float2(u0);
                    float2 f1 = __half22float2(u1);
                    float2 f2 = __half22float2(u2);
                    float2 f3 = __half22float2(u3);
                    ax = fmaf(w0, f0.x, ax); ay = fmaf(w0, f0.y, ay);
                    ax = fmaf(w1, f1.x, ax); ay = fmaf(w1, f1.y, ay);
                    ax = fmaf(w2, f2.x, ax); ay = fmaf(w2, f2.y, ay);
                    ax = fmaf(w3, f3.x, ax); ay = fmaf(w3, f3.y, ay);
                }
            }
            accf[dl][2 * lane]     += ax;       // lane-exclusive, no race
            accf[dl][2 * lane + 1] += ay;
        }
    }
    __syncthreads();

    // bias + relu in place (ch = tc*64 + c)
    for (int i = threadIdx.x; i < DPB * 128; i += 256) {
        int dl = i >> 7, ch = i & 127;
        if (n0 + dl < NN)
            accf[dl][ch] = fmaxf(accf[dl][ch] + b[ch & 63], 0.f);
    }
    __syncthreads();

    // pools: block spans at most 2 graphs (DPB=64 < NPG=200)
    {
        int ch = threadIdx.x & 127;             // tc*64 + c
        int grp = threadIdx.x >> 7;             // 0 or 1
        int g = n0 / NPG + grp;
        int lo = max(n0, g * NPG);
        int hi = min(min(n0 + DPB, NN), (g + 1) * NPG);
        if (lo < hi) {
            float mx = 0.f, sm = 0.f;           // post-relu values >= 0
            for (int nn2 = lo; nn2 < hi; ++nn2) {
                float v = accf[nn2 - n0][ch];
                mx = fmaxf(mx, v);
                sm += v;
            }
            int tc = ch >> 6, c = ch & 63;
            atomicMax((int*)&pmax[tc * GC + g * COUT + c], __float_as_int(mx));
            atomicAdd(&psum[tc * GC + g * COUT + c], sm);
        }
    }

    if (FUSE) {
        // Hout rows = relu_acc . W  (premultiplied for next layer)
        int dl = threadIdx.x >> 2;              // 0..63
        int q  = threadIdx.x & 3;               // tc = q>>1, pr half = q&1
        int n = n0 + dl;
        if (n < NN) {
            int tc = q >> 1;
            int prbase = (q & 1) * 16;
            for (int pp = 0; pp < 16; ++pp) {
                int pr = prbase + pp;
                float b0 = 0.f, bb1 = 0.f;
                #pragma unroll
                for (int k = 0; k < COUT; ++k) {
                    float xv = accf[dl][tc * 64 + k];
                    float2 wv = __half22float2(Ws[k * 32 + pr]);
                    b0 = fmaf(xv, wv.x, b0);
                    bb1 = fmaf(xv, wv.y, bb1);
                }
                Hout[(size_t)n * 64 + tc * 32 + pr] = __floats2half2_rn(b0, bb1);
            }
        }
    }
}

// fold 2-t scratch -> out[:, :, t0..t0+1], reset
__global__ void fold2(float* __restrict__ pmaxT, float* __restrict__ psumT,
                      float* __restrict__ out, int t0) {
    int i = blockIdx.x * 256 + threadIdx.x;
    if (i >= 2 * GC) return;
    int tc = i / GC;
    int r = i - tc * GC;
    int g = r >> 6, c = r & 63;
    float m = pmaxT[tc * GC + r] + pmaxT[2 * GC + tc * GC + r] +
              pmaxT[4 * GC + tc * GC + r];
    float mean = psumT[i] * (1.0f / NPG);
    int t = t0 + tc;
    out[((size_t)g * 128 + c) * TT + t] = m;
    out[((size_t)g * 128 + 64 + c) * TT + t] = mean;
    pmaxT[tc * GC + r] = 0.f;
    pmaxT[2 * GC + tc * GC + r] = 0.f;
    pmaxT[4 * GC + tc * GC + r] = 0.f;
    psumT[i] = 0.f;
}

// ---------------- launch ----------------

extern "C" void kernel_launch(void* const* d_in, const int* in_sizes, int n_in,
                              void* d_out, int out_size, void* d_ws, size_t ws_size,
                              hipStream_t stream) {
    const float* x   = (const float*)d_in[0];
    const int*   ei  = (const int*)d_in[1];
    const int*   src = ei;
    const int*   dst = ei + EE;
    const float* W1  = (const float*)d_in[3];
    const float* b1  = (const float*)d_in[4];
    const float* W2  = (const float*)d_in[5];
    const float* b2  = (const float*)d_in[6];
    const float* W3  = (const float*)d_in[7];
    const float* b3  = (const float*)d_in[8];
    float* out = (float*)d_out;

    char* wsp = (char*)d_ws;
    auto alloc = [&](size_t bytes) {
        char* p = wsp;
        wsp += (bytes + 255) & ~(size_t)255;
        return p;
    };
    // layout (~48.9 MB, ws known >= 51.67 MB):
    // [dinv][off][csrp][H1 12.8M][xa2 25.6M][H2extra 6.4M][scr]
    // H2 = xa2 chunk-3 region + H2extra (contiguous). Chunks processed
    // DESCENDING so chunk 3's xa is consumed before agg2t writes H2.
    const size_t chunkHalf2 = (size_t)NN * 32;
    float*        dinv = (float*)       alloc((size_t)NN * 4);
    int*          off  = (int*)         alloc((size_t)(NN + 1) * 4);
    unsigned int* csrp = (unsigned int*)alloc((size_t)EE * 4);
    __half2*      H1   = (__half2*)     alloc((size_t)NN * 64 * 4);
    __half2*      xa2  = (__half2*)     alloc(chunkHalf2 * 4 * 4);
    __half2*      h2x  = (__half2*)     alloc(chunkHalf2 * 4);
    float*        scr  = (float*)       alloc((size_t)8 * GC * 4);
    (void)h2x;
    __half2* H2 = xa2 + 3 * chunkHalf2;
    float* pmaxT = scr;                   // [layer(3)][tc(2)][GC]
    float* psumT = scr + 6 * GC;          // [tc(2)][GC]

    // setup-only buffers aliased into H1 (dead before H1's first write)
    int* deg    = (int*)H1;
    int* cursor = ((int*)H1) + NN;
    int* bsum   = ((int*)H1) + 2 * NN;

    init_deg<<<NBLK, 256, 0, stream>>>(deg, cursor);
    count_deg<<<(EE + 255) / 256, 256, 0, stream>>>(dst, deg);
    compute_dinv<<<NBLK, 256, 0, stream>>>(deg, dinv);
    scan_blocks<<<NBLK, SCAN_B, 0, stream>>>(deg, off, bsum);
    scan_sums<<<1, SCAN_B, 0, stream>>>(bsum, off);
    scan_add<<<NBLK, SCAN_B, 0, stream>>>(off, bsum);
    fill_csr<<<(EE + 255) / 256, 256, 0, stream>>>(src, dst, off, cursor, dinv, csrp);
    scratch_init<<<(8 * GC + 255) / 256, 256, 0, stream>>>(scr, 8 * GC);

    agg_x_allT16<<<NN / 4, 256, 0, stream>>>(x, off, csrp, dinv, xa2);

    for (int c = 3; c >= 0; --c) {        // descending: frees chunk 3 first
        int t0 = 2 * c;
        const __half2* xc = xa2 + (size_t)c * chunkHalf2;
        l1mat2i<<<NN / 4, 256, 0, stream>>>(xc, W1, b1, W2, H1, pmaxT, psumT);
        agg2t<1><<<NDB, 256, 0, stream>>>(H1, off, csrp, dinv, b2, W3, H2,
                                          pmaxT + 2 * GC, psumT);
        agg2t<0><<<NDB, 256, 0, stream>>>(H2, off, csrp, dinv, b3, nullptr, nullptr,
                                          pmaxT + 4 * GC, psumT);
        fold2<<<(2 * GC + 255) / 256, 256, 0, stream>>>(pmaxT, psumT, out, t0);
    }
}

// Round 5
// 823.009 us; speedup vs baseline: 2.8760x; 2.8760x over previous
//
#include <hip/hip_runtime.h>
#include <hip/hip_fp16.h>
#include <math.h>

#define NN 50000
#define EE 800000
#define BB 250
#define TT 8
#define CIN 32
#define COUT 64
#define NPG 200          // nodes per graph (N/B)
#define SCAN_B 256
#define NBLK 196         // ceil(50000/256)
#define GC (BB * COUT)   // 16000 floats per pool slab

// pack/unpack CSR entry: low 16 = src node (NN<65536), high 16 = fp16 weight
__device__ __forceinline__ float unpack_w(unsigned int v) {
    union { unsigned short u; __half h; } cv;
    cv.u = (unsigned short)(v >> 16);
    return __half2float(cv.h);
}

// ---------------- setup kernels (graph structure, once per call) ----------------

__global__ void init_deg(int* deg, int* cursor) {
    int n = blockIdx.x * 256 + threadIdx.x;
    if (n < NN) { deg[n] = 1; cursor[n] = 0; }
}

__global__ void count_deg(const int* dst, int* deg) {
    int e = blockIdx.x * 256 + threadIdx.x;
    if (e < EE) atomicAdd(&deg[dst[e]], 1);
}

__global__ void compute_dinv(const int* deg, float* dinv) {
    int n = blockIdx.x * 256 + threadIdx.x;
    if (n < NN) dinv[n] = rsqrtf((float)deg[n]);
}

__global__ void scan_blocks(const int* deg, int* off, int* bsum) {
    __shared__ int sh[SCAN_B];
    int gid = blockIdx.x * SCAN_B + threadIdx.x;
    int v = (gid < NN) ? (deg[gid] - 1) : 0;
    sh[threadIdx.x] = v;
    __syncthreads();
    for (int s = 1; s < SCAN_B; s <<= 1) {
        int add = (threadIdx.x >= s) ? sh[threadIdx.x - s] : 0;
        __syncthreads();
        sh[threadIdx.x] += add;
        __syncthreads();
    }
    if (gid < NN) off[gid] = sh[threadIdx.x] - v;
    if (threadIdx.x == SCAN_B - 1) bsum[blockIdx.x] = sh[threadIdx.x];
}

__global__ void scan_sums(int* bsum, int* off) {
    __shared__ int sh[SCAN_B];
    int v = (threadIdx.x < NBLK) ? bsum[threadIdx.x] : 0;
    sh[threadIdx.x] = v;
    __syncthreads();
    for (int s = 1; s < SCAN_B; s <<= 1) {
        int add = (threadIdx.x >= s) ? sh[threadIdx.x - s] : 0;
        __syncthreads();
        sh[threadIdx.x] += add;
        __syncthreads();
    }
    if (threadIdx.x < NBLK) bsum[threadIdx.x] = sh[threadIdx.x] - v;
    if (threadIdx.x == 0) off[NN] = EE;
}

__global__ void scan_add(int* off, const int* bsum) {
    int gid = blockIdx.x * SCAN_B + threadIdx.x;
    if (gid < NN) off[gid] += bsum[blockIdx.x];
}

__global__ void fill_csr(const int* src, const int* dst, const int* off,
                         int* cursor, const float* dinv, unsigned int* csrp) {
    int e = blockIdx.x * 256 + threadIdx.x;
    if (e >= EE) return;
    int s = src[e], d = dst[e];
    int p = atomicAdd(&cursor[d], 1);
    union { __half h; unsigned short u; } cv;
    cv.h = __float2half(dinv[s] * dinv[d]);
    csrp[off[d] + p] = (unsigned int)s | ((unsigned int)cv.u << 16);
}

__global__ void scratch_init(float* scr, int ntot) {
    int i = blockIdx.x * 256 + threadIdx.x;
    if (i < ntot) scr[i] = 0.f;
}

// ---------------- compute kernels ----------------

// ONE pass over edges: xa2 chunk-interleaved fp16. Broadcast walk (16B/lane).
__global__ void agg_x_allT16(const float* __restrict__ x, const int* __restrict__ off,
                             const unsigned int* __restrict__ csrp,
                             const float* __restrict__ dinv, __half2* __restrict__ xa2) {
    int lane = threadIdx.x & 63;
    int w = threadIdx.x >> 6;
    int n = blockIdx.x * 4 + w;
    float dn = dinv[n];
    float sw = dn * dn;
    float4 v = ((const float4*)(x + (size_t)n * 256))[lane];
    float4 acc = make_float4(sw * v.x, sw * v.y, sw * v.z, sw * v.w);
    int e0 = off[n], e1 = off[n + 1];
    for (int base = e0; base < e1; base += 64) {
        int idx = base + lane;
        unsigned int cme = (idx < e1) ? csrp[idx] : 0u;
        int cnt = min(64, e1 - base);
        int k = 0;
        for (; k + 3 < cnt; k += 4) {
            unsigned int p0 = __shfl(cme, k, 64),     p1 = __shfl(cme, k + 1, 64);
            unsigned int p2 = __shfl(cme, k + 2, 64), p3 = __shfl(cme, k + 3, 64);
            float4 u0 = ((const float4*)(x + (size_t)(p0 & 0xffff) * 256))[lane];
            float4 u1 = ((const float4*)(x + (size_t)(p1 & 0xffff) * 256))[lane];
            float4 u2 = ((const float4*)(x + (size_t)(p2 & 0xffff) * 256))[lane];
            float4 u3 = ((const float4*)(x + (size_t)(p3 & 0xffff) * 256))[lane];
            float w0 = unpack_w(p0), w1 = unpack_w(p1);
            float w2 = unpack_w(p2), w3 = unpack_w(p3);
            acc.x = fmaf(w0, u0.x, acc.x); acc.y = fmaf(w0, u0.y, acc.y);
            acc.z = fmaf(w0, u0.z, acc.z); acc.w = fmaf(w0, u0.w, acc.w);
            acc.x = fmaf(w1, u1.x, acc.x); acc.y = fmaf(w1, u1.y, acc.y);
            acc.z = fmaf(w1, u1.z, acc.z); acc.w = fmaf(w1, u1.w, acc.w);
            acc.x = fmaf(w2, u2.x, acc.x); acc.y = fmaf(w2, u2.y, acc.y);
            acc.z = fmaf(w2, u2.z, acc.z); acc.w = fmaf(w2, u2.w, acc.w);
            acc.x = fmaf(w3, u3.x, acc.x); acc.y = fmaf(w3, u3.y, acc.y);
            acc.z = fmaf(w3, u3.z, acc.z); acc.w = fmaf(w3, u3.w, acc.w);
        }
        for (; k < cnt; ++k) {
            unsigned int p = __shfl(cme, k, 64);
            float wj = unpack_w(p);
            float4 u = ((const float4*)(x + (size_t)(p & 0xffff) * 256))[lane];
            acc.x = fmaf(wj, u.x, acc.x); acc.y = fmaf(wj, u.y, acc.y);
            acc.z = fmaf(wj, u.z, acc.z); acc.w = fmaf(wj, u.w, acc.w);
        }
    }
    // element flat idx f = 4*lane+k -> (c = f>>3, t = f&7)
    __shared__ float sh[4][TT][33];
    float av[4] = {acc.x, acc.y, acc.z, acc.w};
    #pragma unroll
    for (int k = 0; k < 4; ++k) {
        int f = 4 * lane + k;
        sh[w][f & 7][f >> 3] = av[k];
    }
    __syncthreads();
    // chunk-interleaved write: addr = (chunk*NN + n)*32 + tc*16 + pp
    for (int i = threadIdx.x; i < 512; i += 256) {
        int t = i >> 6;
        int r = i & 63;
        int nl = r >> 4;
        int pp = r & 15;
        xa2[((size_t)(t >> 1) * NN + blockIdx.x * 4 + nl) * 32 + (t & 1) * 16 + pp] =
            __floats2half2_rn(sh[nl][t][2 * pp], sh[nl][t][2 * pp + 1]);
    }
}

// h1 = relu(xa[chunk] W1 + b1), pool, H1[n][tc][pr] = h1 W2 (interleaved out)
__global__ void l1mat2i(const __half2* __restrict__ xa, const float* __restrict__ W1,
                        const float* __restrict__ b1, const float* __restrict__ W2,
                        __half2* __restrict__ H1,
                        float* __restrict__ pmax, float* __restrict__ psum) {
    __shared__ float W1s[CIN * COUT];      // 8 KB
    __shared__ __half2 W2s[COUT * 32];     // 8 KB
    __shared__ float Xs[4][2][CIN];
    __shared__ float tile[4][2][COUT];
    for (int i = threadIdx.x; i < CIN * COUT; i += 256) W1s[i] = W1[i];
    for (int i = threadIdx.x; i < COUT * 32; i += 256) {
        int k = i >> 5, pr = i & 31;
        W2s[i] = __floats2half2_rn(W2[k * COUT + 2 * pr], W2[k * COUT + 2 * pr + 1]);
    }
    if (threadIdx.x < 128) {
        int nl = threadIdx.x >> 5, idx = threadIdx.x & 31;
        int tc = idx >> 4, pp = idx & 15;
        float2 v = __half22float2(xa[((size_t)blockIdx.x * 4 + nl) * 32 + idx]);
        Xs[nl][tc][2 * pp] = v.x;
        Xs[nl][tc][2 * pp + 1] = v.y;
    }
    __syncthreads();
    int co = threadIdx.x & 63;
    int nl = threadIdx.x >> 6;
    float a0 = b1[co], a1 = b1[co];
    #pragma unroll
    for (int k = 0; k < CIN; ++k) {
        float wv = W1s[k * COUT + co];
        a0 = fmaf(Xs[nl][0][k], wv, a0);
        a1 = fmaf(Xs[nl][1][k], wv, a1);
    }
    tile[nl][0][co] = fmaxf(a0, 0.f);
    tile[nl][1][co] = fmaxf(a1, 0.f);
    __syncthreads();
    if (threadIdx.x < 128) {
        int c = threadIdx.x & 63, tc = threadIdx.x >> 6;
        float m = fmaxf(fmaxf(tile[0][tc][c], tile[1][tc][c]),
                        fmaxf(tile[2][tc][c], tile[3][tc][c]));
        float s = tile[0][tc][c] + tile[1][tc][c] + tile[2][tc][c] + tile[3][tc][c];
        int g = blockIdx.x / 50;
        atomicMax((int*)&pmax[tc * GC + g * COUT + c], __float_as_int(m));
        atomicAdd(&psum[tc * GC + g * COUT + c], s);
    }
    {   // W2 matmul: 256 thr = 8 rows (4 nodes x 2 tc) x 32 pairs
        int row = threadIdx.x >> 5;
        int pr = threadIdx.x & 31;
        int nl2 = row >> 1, tc2 = row & 1;
        float b0 = 0.f, bb1 = 0.f;
        #pragma unroll
        for (int k = 0; k < COUT; ++k) {
            float xv = tile[nl2][tc2][k];
            float2 wv = __half22float2(W2s[k * 32 + pr]);
            b0 = fmaf(xv, wv.x, b0);
            bb1 = fmaf(xv, wv.y, bb1);
        }
        H1[((size_t)blockIdx.x * 4 + nl2) * 64 + tc2 * 32 + pr] =
            __floats2half2_rn(b0, bb1);
    }
}

// Quad-edge 2-t aggregation: lane = (edge-in-quad sub, 16B-offset qoff).
// ONE global_load_dwordx4 per wave fetches FOUR edges' 256B rows (16B/lane).
// Round-0..3 pass is UNCONDITIONAL and self-masking: lanes >= cnt carry cme=0,
// so the shfl'd entry has weight 0.0 (fp16 zero) and address row 0 (valid).
// shfl_xor(16,32) reduces edge groups. Measured 73 us/launch = 205 MB at
// ~2.8 TB/s from the L3-resident H set — at the L3 random-granule ceiling
// (r2-r4 established: granule shape/ILP immaterial, bytes/s invariant).
template <int FUSE>
__global__ void agg2q(const __half2* __restrict__ Hin, const int* __restrict__ off,
                      const unsigned int* __restrict__ csrp,
                      const float* __restrict__ dinv, const float* __restrict__ b,
                      const float* __restrict__ W, __half2* __restrict__ Hout,
                      float* __restrict__ pmax, float* __restrict__ psum) {
    __shared__ __half2 Ws[FUSE ? COUT * 32 : 1];
    __shared__ float tile[4][2][COUT];
    if (FUSE)
        for (int i = threadIdx.x; i < COUT * 32; i += 256) {
            int k = i >> 5, pr = i & 31;
            Ws[i] = __floats2half2_rn(W[k * COUT + 2 * pr], W[k * COUT + 2 * pr + 1]);
        }
    int lane = threadIdx.x & 63;
    int sub = lane >> 4;       // which edge within quad
    int qoff = lane & 15;      // float4 slot within 256B row
    int w = threadIdx.x >> 6;
    int n = blockIdx.x * 4 + w;
    int e0 = off[n], e1 = off[n + 1];
    float dn = dinv[n];                     // hoisted: latency hides under gather
    union F4H { float4 f; __half2 h[4]; };
    F4H su;                                 // self-loop row, issued early
    su.f = make_float4(0.f, 0.f, 0.f, 0.f);
    if (sub == 0) su.f = ((const float4*)(Hin + (size_t)n * 64))[qoff];
    float a0 = 0.f, a1 = 0.f, a2 = 0.f, a3 = 0.f;
    float a4 = 0.f, a5 = 0.f, a6 = 0.f, a7 = 0.f;

#define ACCUM(U, WV)                                              \
    {                                                             \
        float2 f0 = __half22float2(U.h[0]);                       \
        float2 f1 = __half22float2(U.h[1]);                       \
        float2 f2 = __half22float2(U.h[2]);                       \
        float2 f3 = __half22float2(U.h[3]);                       \
        a0 = fmaf(WV, f0.x, a0); a1 = fmaf(WV, f0.y, a1);         \
        a2 = fmaf(WV, f1.x, a2); a3 = fmaf(WV, f1.y, a3);         \
        a4 = fmaf(WV, f2.x, a4); a5 = fmaf(WV, f2.y, a5);         \
        a6 = fmaf(WV, f3.x, a6); a7 = fmaf(WV, f3.y, a7);         \
    }

    for (int base = e0; base < e1; base += 64) {
        int idx = base + lane;
        unsigned int cme = (idx < e1) ? csrp[idx] : 0u;   // 1 load / 64 edges
        int cnt = min(64, e1 - base);
        // ---- rounds 0..3 unconditional (16 edges, self-masking tail) ----
        unsigned int ce0 = __shfl(cme, sub,      64);
        unsigned int ce1 = __shfl(cme, sub + 4,  64);
        unsigned int ce2 = __shfl(cme, sub + 8,  64);
        unsigned int ce3 = __shfl(cme, sub + 12, 64);
        F4H u0, u1, u2, u3;
        u0.f = ((const float4*)(Hin + (size_t)(ce0 & 0xffff) * 64))[qoff];
        u1.f = ((const float4*)(Hin + (size_t)(ce1 & 0xffff) * 64))[qoff];
        u2.f = ((const float4*)(Hin + (size_t)(ce2 & 0xffff) * 64))[qoff];
        u3.f = ((const float4*)(Hin + (size_t)(ce3 & 0xffff) * 64))[qoff];
        float w0 = unpack_w(ce0), w1 = unpack_w(ce1);
        float w2 = unpack_w(ce2), w3 = unpack_w(ce3);
        ACCUM(u0, w0);
        ACCUM(u1, w1);
        ACCUM(u2, w2);
        ACCUM(u3, w3);
        // ---- remainder rounds (deg > 16 within this window), self-masking ----
        int R = (cnt + 3) >> 2;
        for (int r = 4; r < R; ++r) {
            unsigned int ce = __shfl(cme, 4 * r + sub, 64);
            float wv = unpack_w(ce);          // ce=0 -> wv=0, row 0 valid
            F4H u;
            u.f = ((const float4*)(Hin + (size_t)(ce & 0xffff) * 64))[qoff];
            ACCUM(u, wv);
        }
    }
#undef ACCUM
    // reduce the 4 edge groups (lanes with same qoff)
    a0 += __shfl_xor(a0, 16, 64); a0 += __shfl_xor(a0, 32, 64);
    a1 += __shfl_xor(a1, 16, 64); a1 += __shfl_xor(a1, 32, 64);
    a2 += __shfl_xor(a2, 16, 64); a2 += __shfl_xor(a2, 32, 64);
    a3 += __shfl_xor(a3, 16, 64); a3 += __shfl_xor(a3, 32, 64);
    a4 += __shfl_xor(a4, 16, 64); a4 += __shfl_xor(a4, 32, 64);
    a5 += __shfl_xor(a5, 16, 64); a5 += __shfl_xor(a5, 32, 64);
    a6 += __shfl_xor(a6, 16, 64); a6 += __shfl_xor(a6, 32, 64);
    a7 += __shfl_xor(a7, 16, 64); a7 += __shfl_xor(a7, 32, 64);
    if (sub == 0) {
        // self-loop + bias + relu; lane qoff owns row half2 slots 4q..4q+3
        float sw = dn * dn;
        float acc[8] = {a0, a1, a2, a3, a4, a5, a6, a7};
        #pragma unroll
        for (int i = 0; i < 4; ++i) {
            int h = 4 * qoff + i;
            int tcc = h >> 5;
            int p = h & 31;
            float2 sv = __half22float2(su.h[i]);
            float ox = fmaxf(fmaf(sw, sv.x, acc[2 * i])     + b[2 * p],     0.f);
            float oy = fmaxf(fmaf(sw, sv.y, acc[2 * i + 1]) + b[2 * p + 1], 0.f);
            tile[w][tcc][2 * p] = ox;
            tile[w][tcc][2 * p + 1] = oy;
        }
    }
    __syncthreads();
    if (threadIdx.x < 128) {
        int c = threadIdx.x & 63, tcc = threadIdx.x >> 6;
        float m = fmaxf(fmaxf(tile[0][tcc][c], tile[1][tcc][c]),
                        fmaxf(tile[2][tcc][c], tile[3][tcc][c]));
        float s = tile[0][tcc][c] + tile[1][tcc][c] + tile[2][tcc][c] + tile[3][tcc][c];
        int g = blockIdx.x / 50;
        atomicMax((int*)&pmax[tcc * GC + g * COUT + c], __float_as_int(m));
        atomicAdd(&psum[tcc * GC + g * COUT + c], s);
    }
    if (FUSE) {
        int row = threadIdx.x >> 5;
        int pr = threadIdx.x & 31;
        int nl2 = row >> 1, tc2 = row & 1;
        float b0 = 0.f, bb1 = 0.f;
        #pragma unroll
        for (int k = 0; k < COUT; ++k) {
            float xv = tile[nl2][tc2][k];
            float2 wv = __half22float2(Ws[k * 32 + pr]);
            b0 = fmaf(xv, wv.x, b0);
            bb1 = fmaf(xv, wv.y, bb1);
        }
        Hout[((size_t)blockIdx.x * 4 + nl2) * 64 + tc2 * 32 + pr] =
            __floats2half2_rn(b0, bb1);
    }
}

// fold 2-t scratch -> out[:, :, t0..t0+1], reset
__global__ void fold2(float* __restrict__ pmaxT, float* __restrict__ psumT,
                      float* __restrict__ out, int t0) {
    int i = blockIdx.x * 256 + threadIdx.x;
    if (i >= 2 * GC) return;
    int tc = i / GC;
    int r = i - tc * GC;
    int g = r >> 6, c = r & 63;
    float m = pmaxT[tc * GC + r] + pmaxT[2 * GC + tc * GC + r] +
              pmaxT[4 * GC + tc * GC + r];
    float mean = psumT[i] * (1.0f / NPG);
    int t = t0 + tc;
    out[((size_t)g * 128 + c) * TT + t] = m;
    out[((size_t)g * 128 + 64 + c) * TT + t] = mean;
    pmaxT[tc * GC + r] = 0.f;
    pmaxT[2 * GC + tc * GC + r] = 0.f;
    pmaxT[4 * GC + tc * GC + r] = 0.f;
    psumT[i] = 0.f;
}

// ---------------- launch ----------------

extern "C" void kernel_launch(void* const* d_in, const int* in_sizes, int n_in,
                              void* d_out, int out_size, void* d_ws, size_t ws_size,
                              hipStream_t stream) {
    const float* x   = (const float*)d_in[0];
    const int*   ei  = (const int*)d_in[1];
    const int*   src = ei;
    const int*   dst = ei + EE;
    const float* W1  = (const float*)d_in[3];
    const float* b1  = (const float*)d_in[4];
    const float* W2  = (const float*)d_in[5];
    const float* b2  = (const float*)d_in[6];
    const float* W3  = (const float*)d_in[7];
    const float* b3  = (const float*)d_in[8];
    float* out = (float*)d_out;

    char* wsp = (char*)d_ws;
    auto alloc = [&](size_t bytes) {
        char* p = wsp;
        wsp += (bytes + 255) & ~(size_t)255;
        return p;
    };
    // layout (~48.9 MB, ws known >= 51.67 MB):
    // [dinv][off][csrp][H1 12.8M][xa2 25.6M][H2extra 6.4M][scr]
    // H2 = xa2 chunk-3 region + H2extra (contiguous). Chunks processed
    // DESCENDING so chunk 3's xa is consumed before agg2q writes H2.
    const size_t chunkHalf2 = (size_t)NN * 32;
    float*        dinv = (float*)       alloc((size_t)NN * 4);
    int*          off  = (int*)         alloc((size_t)(NN + 1) * 4);
    unsigned int* csrp = (unsigned int*)alloc((size_t)EE * 4);
    __half2*      H1   = (__half2*)     alloc((size_t)NN * 64 * 4);
    __half2*      xa2  = (__half2*)     alloc(chunkHalf2 * 4 * 4);
    __half2*      h2x  = (__half2*)     alloc(chunkHalf2 * 4);
    float*        scr  = (float*)       alloc((size_t)8 * GC * 4);
    (void)h2x;
    __half2* H2 = xa2 + 3 * chunkHalf2;
    float* pmaxT = scr;                   // [layer(3)][tc(2)][GC]
    float* psumT = scr + 6 * GC;          // [tc(2)][GC]

    // setup-only buffers aliased into H1 (dead before H1's first write)
    int* deg    = (int*)H1;
    int* cursor = ((int*)H1) + NN;
    int* bsum   = ((int*)H1) + 2 * NN;

    init_deg<<<NBLK, 256, 0, stream>>>(deg, cursor);
    count_deg<<<(EE + 255) / 256, 256, 0, stream>>>(dst, deg);
    compute_dinv<<<NBLK, 256, 0, stream>>>(deg, dinv);
    scan_blocks<<<NBLK, SCAN_B, 0, stream>>>(deg, off, bsum);
    scan_sums<<<1, SCAN_B, 0, stream>>>(bsum, off);
    scan_add<<<NBLK, SCAN_B, 0, stream>>>(off, bsum);
    fill_csr<<<(EE + 255) / 256, 256, 0, stream>>>(src, dst, off, cursor, dinv, csrp);
    scratch_init<<<(8 * GC + 255) / 256, 256, 0, stream>>>(scr, 8 * GC);

    agg_x_allT16<<<NN / 4, 256, 0, stream>>>(x, off, csrp, dinv, xa2);

    for (int c = 3; c >= 0; --c) {        // descending: frees chunk 3 first
        int t0 = 2 * c;
        const __half2* xc = xa2 + (size_t)c * chunkHalf2;
        l1mat2i<<<NN / 4, 256, 0, stream>>>(xc, W1, b1, W2, H1, pmaxT, psumT);
        agg2q<1><<<NN / 4, 256, 0, stream>>>(H1, off, csrp, dinv, b2, W3, H2,
                                             pmaxT + 2 * GC, psumT);
        agg2q<0><<<NN / 4, 256, 0, stream>>>(H2, off, csrp, dinv, b3, nullptr, nullptr,
                                             pmaxT + 4 * GC, psumT);
        fold2<<<(2 * GC + 255) / 256, 256, 0, stream>>>(pmaxT, psumT, out, t0);
    }
}